// Round 3
// baseline (464.200 us; speedup 1.0000x reference)
//
#include <hip/hip_runtime.h>
#include <math.h>

#define H  1024
#define B  64
#define T  1024
#define BT (B*T)       // 65536
#define TC 32          // t-columns per block-chunk (128 B per row = full L2 line)
#define SPLIT 8        // blocks per b
#define CHUNKS 4       // T/(TC*SPLIT)
#define NT 512         // threads per block (8 waves)

__device__ __forceinline__ float ex2(float x) { return __builtin_amdgcn_exp2f(x); }

// One block = (b, split). Per chunk: 1024 rows x 32 t held ENTIRELY in
// registers (thread owns 16 rows x 4 t = 64 floats).
// Software pipeline: chunk c+1's loads are issued inside chunk c's P3
// (each v[i] is reloaded in place right after its last use). Plain
// register loads cross the s_barrier without a vmcnt(0) drain, so HBM
// streaming continues through the reduce/exp phases -> ~95% HBM duty.
__global__ __launch_bounds__(NT, 4) void attn_main(const float* __restrict__ dec,
                                                   const float* __restrict__ enc,
                                                   float* __restrict__ ws)
{
    __shared__ float rbuf[3][8][TC];   // [qty][wave][t]  3 KB
    __shared__ float prm[2][TC];       // per-t params (s*log2e, m*log2e) / recip

    const int tid   = threadIdx.x;
    const int split = blockIdx.x;
    const int b     = blockIdx.y;
    const int lane  = tid & 63;
    const int wave  = tid >> 6;        // 0..7
    const int r     = tid >> 3;        // 0..63 ; rows h = r + 64*i, i=0..15
    const int c8    = tid & 7;         // float4 group: t_local = c8*4..c8*4+3

    const float L2E = 1.44269504088896340736f;

    float acc[16];
    #pragma unroll
    for (int i = 0; i < 16; ++i) acc[i] = 0.f;

    // column base for this thread (t varies by chunk)
    const float* ebase = enc + (size_t)b*T + 4*c8;
    const int t0_first = split * CHUNKS * TC;

    // -------- prologue: issue chunk 0's loads --------
    float4 v[16];
    #pragma unroll
    for (int i = 0; i < 16; ++i) {
        const int h = r + 64*i;
        v[i] = *reinterpret_cast<const float4*>(ebase + (size_t)h*BT + t0_first);
    }

    for (int c = 0; c < CHUNKS; ++c) {
        const int t0 = t0_first + c * TC;

        // ---------- P1 compute: dot + max + min (waits vmcnt as needed) ----
        float4 s4  = make_float4(0.f, 0.f, 0.f, 0.f);
        float4 mx4 = make_float4(-INFINITY, -INFINITY, -INFINITY, -INFINITY);
        float4 mn4 = make_float4( INFINITY,  INFINITY,  INFINITY,  INFINITY);
        #pragma unroll
        for (int i = 0; i < 16; ++i) {
            const int h = r + 64*i;
            const float dh = dec[b*H + h];
            s4.x = fmaf(v[i].x, dh, s4.x); s4.y = fmaf(v[i].y, dh, s4.y);
            s4.z = fmaf(v[i].z, dh, s4.z); s4.w = fmaf(v[i].w, dh, s4.w);
            mx4.x = fmaxf(mx4.x, v[i].x); mx4.y = fmaxf(mx4.y, v[i].y);
            mx4.z = fmaxf(mx4.z, v[i].z); mx4.w = fmaxf(mx4.w, v[i].w);
            mn4.x = fminf(mn4.x, v[i].x); mn4.y = fminf(mn4.y, v[i].y);
            mn4.z = fminf(mn4.z, v[i].z); mn4.w = fminf(mn4.w, v[i].w);
        }
        // reduce over the wave's 8 r-groups (stride-8 lanes share c8)
        #pragma unroll
        for (int off = 8; off <= 32; off <<= 1) {
            s4.x += __shfl_xor(s4.x, off); s4.y += __shfl_xor(s4.y, off);
            s4.z += __shfl_xor(s4.z, off); s4.w += __shfl_xor(s4.w, off);
            mx4.x = fmaxf(mx4.x, __shfl_xor(mx4.x, off)); mx4.y = fmaxf(mx4.y, __shfl_xor(mx4.y, off));
            mx4.z = fmaxf(mx4.z, __shfl_xor(mx4.z, off)); mx4.w = fmaxf(mx4.w, __shfl_xor(mx4.w, off));
            mn4.x = fminf(mn4.x, __shfl_xor(mn4.x, off)); mn4.y = fminf(mn4.y, __shfl_xor(mn4.y, off));
            mn4.z = fminf(mn4.z, __shfl_xor(mn4.z, off)); mn4.w = fminf(mn4.w, __shfl_xor(mn4.w, off));
        }
        if (lane < 8) {   // lane == c8 representative
            *reinterpret_cast<float4*>(&rbuf[0][wave][lane*4]) = s4;
            *reinterpret_cast<float4*>(&rbuf[1][wave][lane*4]) = mx4;
            *reinterpret_cast<float4*>(&rbuf[2][wave][lane*4]) = mn4;
        }
        __syncthreads();
        if (tid < TC) {
            float s  = rbuf[0][0][tid];
            float mx = rbuf[1][0][tid];
            float mn = rbuf[2][0][tid];
            #pragma unroll
            for (int w = 1; w < 8; ++w) {
                s += rbuf[0][w][tid];
                mx = fmaxf(mx, rbuf[1][w][tid]);
                mn = fminf(mn, rbuf[2][w][tid]);
            }
            const float m = (s >= 0.f) ? s*mx : s*mn;   // true max_h(e*s)
            prm[0][tid] = s * L2E;
            prm[1][tid] = m * L2E;
        }
        __syncthreads();

        // ---------- P2: exp in place (registers) + denominator ----------
        {
            const float4 sv = *reinterpret_cast<const float4*>(&prm[0][c8*4]);
            const float4 mv = *reinterpret_cast<const float4*>(&prm[1][c8*4]);
            float4 d4 = make_float4(0.f, 0.f, 0.f, 0.f);
            #pragma unroll
            for (int i = 0; i < 16; ++i) {
                v[i].x = ex2(fmaf(v[i].x, sv.x, -mv.x));
                v[i].y = ex2(fmaf(v[i].y, sv.y, -mv.y));
                v[i].z = ex2(fmaf(v[i].z, sv.z, -mv.z));
                v[i].w = ex2(fmaf(v[i].w, sv.w, -mv.w));
                d4.x += v[i].x; d4.y += v[i].y; d4.z += v[i].z; d4.w += v[i].w;
            }
            #pragma unroll
            for (int off = 8; off <= 32; off <<= 1) {
                d4.x += __shfl_xor(d4.x, off); d4.y += __shfl_xor(d4.y, off);
                d4.z += __shfl_xor(d4.z, off); d4.w += __shfl_xor(d4.w, off);
            }
            if (lane < 8)
                *reinterpret_cast<float4*>(&rbuf[0][wave][lane*4]) = d4;
        }
        __syncthreads();
        if (tid < TC) {
            float d = rbuf[0][0][tid];
            #pragma unroll
            for (int w = 1; w < 8; ++w) d += rbuf[0][w][tid];
            prm[0][tid] = 1.0f / d;
        }
        __syncthreads();

        // ---------- P3: acc += ev * r_t, fused with chunk c+1 prefetch ----
        {
            const float4 rv = *reinterpret_cast<const float4*>(&prm[0][c8*4]);
            if (c + 1 < CHUNKS) {
                const size_t tn = (size_t)(t0 + TC);
                #pragma unroll
                for (int i = 0; i < 16; ++i) {
                    const int h = r + 64*i;
                    acc[i] = fmaf(v[i].x, rv.x, acc[i]);
                    acc[i] = fmaf(v[i].y, rv.y, acc[i]);
                    acc[i] = fmaf(v[i].z, rv.z, acc[i]);
                    acc[i] = fmaf(v[i].w, rv.w, acc[i]);
                    v[i] = *reinterpret_cast<const float4*>(ebase + (size_t)h*BT + tn);
                }
            } else {
                #pragma unroll
                for (int i = 0; i < 16; ++i) {
                    acc[i] = fmaf(v[i].x, rv.x, acc[i]);
                    acc[i] = fmaf(v[i].y, rv.y, acc[i]);
                    acc[i] = fmaf(v[i].z, rv.z, acc[i]);
                    acc[i] = fmaf(v[i].w, rv.w, acc[i]);
                }
            }
        }
        __syncthreads();   // protect prm/rbuf before next chunk's writes
                           // (register prefetch loads stay in flight across this)
    }

    // reduce acc over the 8 c8-groups (lanes sharing r), then write partials
    #pragma unroll
    for (int i = 0; i < 16; ++i) {
        acc[i] += __shfl_xor(acc[i], 1);
        acc[i] += __shfl_xor(acc[i], 2);
        acc[i] += __shfl_xor(acc[i], 4);
    }
    const size_t wbase = (size_t)(b * SPLIT + split) * H;
    #pragma unroll
    for (int i = 0; i < 16; ++i) {
        if ((i >> 1) == c8)           // each lane stores 2 of the 16 rows
            ws[wbase + r + 64*i] = acc[i];
    }
}

// Reduce the 8 split-partials per (b,h).
__global__ __launch_bounds__(256) void attn_reduce(const float* __restrict__ ws,
                                                   float* __restrict__ out)
{
    const int idx = blockIdx.x * 256 + threadIdx.x;   // 0 .. B*H-1
    const int b = idx >> 10;
    const int h = idx & 1023;
    float s = 0.f;
    #pragma unroll
    for (int sp = 0; sp < SPLIT; ++sp)
        s += ws[(size_t)(b * SPLIT + sp) * H + h];
    out[idx] = s;
}

extern "C" void kernel_launch(void* const* d_in, const int* in_sizes, int n_in,
                              void* d_out, int out_size, void* d_ws, size_t ws_size,
                              hipStream_t stream)
{
    const float* dec = (const float*)d_in[0];   // [B,H]
    const float* enc = (const float*)d_in[1];   // [H,B,T]
    float* out = (float*)d_out;                 // [B,H]
    float* ws  = (float*)d_ws;                  // uses B*SPLIT*H*4 = 2 MB

    attn_main  <<<dim3(SPLIT, B), NT, 0, stream>>>(dec, enc, ws);
    attn_reduce<<<dim3((B*H)/256), 256, 0, stream>>>(ws, out);
}

// Round 4
// 376.592 us; speedup vs baseline: 1.2326x; 1.2326x over previous
//
#include <hip/hip_runtime.h>
#include <math.h>

#define H  1024
#define B  64
#define T  1024
#define BT (B*T)       // 65536
#define TC 32          // t-columns per block-chunk (128 B per row = full L2 line)
#define SPLIT 8        // blocks per b
#define CHUNKS 4       // T/(TC*SPLIT)
#define NT 512         // threads per block (8 waves)

__device__ __forceinline__ float ex2(float x) { return __builtin_amdgcn_exp2f(x); }

// One block = (b, split). Per chunk: 1024 rows x 32 t held ENTIRELY in
// registers (thread owns 16 rows x 4 t = 64 floats = 64 VGPRs of data).
// REGISTER BUDGET IS THE WHOLE GAME HERE: live set ~110 VGPRs.
//   - R3's __launch_bounds__(512,4) empirically capped VGPRs at 64
//     (arg2 behaved as min-BLOCKS/CU: 4 blk x 8 waves = 8 waves/SIMD -> 64)
//     and spilled 231 MB to scratch (WRITE_SIZE counter).
//   - amdgpu_waves_per_eu(4) requests exactly 4 waves/EU -> 128-VGPR cap,
//     fits the ~110 live set with zero spill, still 2 blocks/CU (grid-limited
//     occupancy, so the relaxed cap costs nothing).
// No software prefetch: issuing next chunk's 16 float4 loads while v[] is
// still live doubles peak pressure past any achievable cap (R3 post-mortem).
__global__ __launch_bounds__(NT)
__attribute__((amdgpu_waves_per_eu(4)))
void attn_main(const float* __restrict__ dec,
               const float* __restrict__ enc,
               float* __restrict__ ws)
{
    __shared__ float rbuf[3][8][TC];   // [qty][wave][t]  3 KB
    __shared__ float prm[2][TC];       // per-t params (s*log2e, m*log2e) / recip

    const int tid   = threadIdx.x;
    const int split = blockIdx.x;
    const int b     = blockIdx.y;
    const int lane  = tid & 63;
    const int wave  = tid >> 6;        // 0..7
    const int r     = tid >> 3;        // 0..63 ; rows h = r + 64*i, i=0..15
    const int c8    = tid & 7;         // float4 group: t_local = c8*4..c8*4+3

    const float L2E = 1.44269504088896340736f;

    float acc[16];
    #pragma unroll
    for (int i = 0; i < 16; ++i) acc[i] = 0.f;

    for (int c = 0; c < CHUNKS; ++c) {
        const int t0 = (split * CHUNKS + c) * TC;

        // ---------- P1: load (full 128B lines) + dot + max + min ----------
        float4 v[16];
        float4 s4  = make_float4(0.f, 0.f, 0.f, 0.f);
        float4 mx4 = make_float4(-INFINITY, -INFINITY, -INFINITY, -INFINITY);
        float4 mn4 = make_float4( INFINITY,  INFINITY,  INFINITY,  INFINITY);
        #pragma unroll
        for (int i = 0; i < 16; ++i) {
            const int h = r + 64*i;
            v[i] = *reinterpret_cast<const float4*>(enc + (size_t)h*BT + b*T + t0 + 4*c8);
            const float dh = dec[b*H + h];
            s4.x = fmaf(v[i].x, dh, s4.x); s4.y = fmaf(v[i].y, dh, s4.y);
            s4.z = fmaf(v[i].z, dh, s4.z); s4.w = fmaf(v[i].w, dh, s4.w);
            mx4.x = fmaxf(mx4.x, v[i].x); mx4.y = fmaxf(mx4.y, v[i].y);
            mx4.z = fmaxf(mx4.z, v[i].z); mx4.w = fmaxf(mx4.w, v[i].w);
            mn4.x = fminf(mn4.x, v[i].x); mn4.y = fminf(mn4.y, v[i].y);
            mn4.z = fminf(mn4.z, v[i].z); mn4.w = fminf(mn4.w, v[i].w);
        }
        // reduce over the wave's 8 r-groups (stride-8 lanes share c8)
        #pragma unroll
        for (int off = 8; off <= 32; off <<= 1) {
            s4.x += __shfl_xor(s4.x, off); s4.y += __shfl_xor(s4.y, off);
            s4.z += __shfl_xor(s4.z, off); s4.w += __shfl_xor(s4.w, off);
            mx4.x = fmaxf(mx4.x, __shfl_xor(mx4.x, off)); mx4.y = fmaxf(mx4.y, __shfl_xor(mx4.y, off));
            mx4.z = fmaxf(mx4.z, __shfl_xor(mx4.z, off)); mx4.w = fmaxf(mx4.w, __shfl_xor(mx4.w, off));
            mn4.x = fminf(mn4.x, __shfl_xor(mn4.x, off)); mn4.y = fminf(mn4.y, __shfl_xor(mn4.y, off));
            mn4.z = fminf(mn4.z, __shfl_xor(mn4.z, off)); mn4.w = fminf(mn4.w, __shfl_xor(mn4.w, off));
        }
        if (lane < 8) {   // lane == c8 representative
            *reinterpret_cast<float4*>(&rbuf[0][wave][lane*4]) = s4;
            *reinterpret_cast<float4*>(&rbuf[1][wave][lane*4]) = mx4;
            *reinterpret_cast<float4*>(&rbuf[2][wave][lane*4]) = mn4;
        }
        __syncthreads();
        if (tid < TC) {
            float s  = rbuf[0][0][tid];
            float mx = rbuf[1][0][tid];
            float mn = rbuf[2][0][tid];
            #pragma unroll
            for (int w = 1; w < 8; ++w) {
                s += rbuf[0][w][tid];
                mx = fmaxf(mx, rbuf[1][w][tid]);
                mn = fminf(mn, rbuf[2][w][tid]);
            }
            const float m = (s >= 0.f) ? s*mx : s*mn;   // true max_h(e*s)
            prm[0][tid] = s * L2E;
            prm[1][tid] = m * L2E;
        }
        __syncthreads();

        // ---------- P2: exp in place (registers) + denominator ----------
        {
            const float4 sv = *reinterpret_cast<const float4*>(&prm[0][c8*4]);
            const float4 mv = *reinterpret_cast<const float4*>(&prm[1][c8*4]);
            float4 d4 = make_float4(0.f, 0.f, 0.f, 0.f);
            #pragma unroll
            for (int i = 0; i < 16; ++i) {
                v[i].x = ex2(fmaf(v[i].x, sv.x, -mv.x));
                v[i].y = ex2(fmaf(v[i].y, sv.y, -mv.y));
                v[i].z = ex2(fmaf(v[i].z, sv.z, -mv.z));
                v[i].w = ex2(fmaf(v[i].w, sv.w, -mv.w));
                d4.x += v[i].x; d4.y += v[i].y; d4.z += v[i].z; d4.w += v[i].w;
            }
            #pragma unroll
            for (int off = 8; off <= 32; off <<= 1) {
                d4.x += __shfl_xor(d4.x, off); d4.y += __shfl_xor(d4.y, off);
                d4.z += __shfl_xor(d4.z, off); d4.w += __shfl_xor(d4.w, off);
            }
            if (lane < 8)
                *reinterpret_cast<float4*>(&rbuf[0][wave][lane*4]) = d4;
        }
        __syncthreads();
        if (tid < TC) {
            float d = rbuf[0][0][tid];
            #pragma unroll
            for (int w = 1; w < 8; ++w) d += rbuf[0][w][tid];
            prm[0][tid] = 1.0f / d;
        }
        __syncthreads();

        // ---------- P3: acc[i] += sum_t ev * r_t (registers only) ----------
        {
            const float4 rv = *reinterpret_cast<const float4*>(&prm[0][c8*4]);
            #pragma unroll
            for (int i = 0; i < 16; ++i) {
                acc[i] = fmaf(v[i].x, rv.x, acc[i]);
                acc[i] = fmaf(v[i].y, rv.y, acc[i]);
                acc[i] = fmaf(v[i].z, rv.z, acc[i]);
                acc[i] = fmaf(v[i].w, rv.w, acc[i]);
            }
        }
        __syncthreads();   // protect prm/rbuf before next chunk's writes
    }

    // reduce acc over the 8 c8-groups (lanes sharing r), then write partials
    #pragma unroll
    for (int i = 0; i < 16; ++i) {
        acc[i] += __shfl_xor(acc[i], 1);
        acc[i] += __shfl_xor(acc[i], 2);
        acc[i] += __shfl_xor(acc[i], 4);
    }
    const size_t wbase = (size_t)(b * SPLIT + split) * H;
    #pragma unroll
    for (int i = 0; i < 16; ++i) {
        if ((i >> 1) == c8)           // each lane stores 2 of the 16 rows
            ws[wbase + r + 64*i] = acc[i];
    }
}

// Reduce the 8 split-partials per (b,h).
__global__ __launch_bounds__(256) void attn_reduce(const float* __restrict__ ws,
                                                   float* __restrict__ out)
{
    const int idx = blockIdx.x * 256 + threadIdx.x;   // 0 .. B*H-1
    const int b = idx >> 10;
    const int h = idx & 1023;
    float s = 0.f;
    #pragma unroll
    for (int sp = 0; sp < SPLIT; ++sp)
        s += ws[(size_t)(b * SPLIT + sp) * H + h];
    out[idx] = s;
}

extern "C" void kernel_launch(void* const* d_in, const int* in_sizes, int n_in,
                              void* d_out, int out_size, void* d_ws, size_t ws_size,
                              hipStream_t stream)
{
    const float* dec = (const float*)d_in[0];   // [B,H]
    const float* enc = (const float*)d_in[1];   // [H,B,T]
    float* out = (float*)d_out;                 // [B,H]
    float* ws  = (float*)d_ws;                  // uses B*SPLIT*H*4 = 2 MB

    attn_main  <<<dim3(SPLIT, B), NT, 0, stream>>>(dec, enc, ws);
    attn_reduce<<<dim3((B*H)/256), 256, 0, stream>>>(ws, out);
}